// Round 7
// baseline (65.398 us; speedup 1.0000x reference)
//
#include <hip/hip_runtime.h>

#define NN 4096
#define NT 1024
#define OVF_L 0xFFFFFFFFFFFFFFFEull

__global__ __launch_bounds__(NT)
void DistanceNMS_kernel(const float* __restrict__ peaks, float* __restrict__ out)
{
    // ---- LDS (~132 KB) ----
    __shared__ uint4 cpk[NN];                   // 64K  cell-ordered {x_bits,y_bits,kb,origidx}
    __shared__ unsigned long long keybuf[NN];   // 32K  bucket-grouped (kb<<32)|origidx
    __shared__ unsigned cellidx[4096];          // 16K  count -> excl start -> END
    __shared__ unsigned buckidx[4096];          // 16K  count -> excl start -> END
    __shared__ unsigned char state_[NN];        //  4K  by orig idx: 0=UNDET 1=KEPT 2=DEAD
    __shared__ unsigned wavesumA[16], wavesumB[16];

    const int tid  = threadIdx.x;
    const int lane = tid & 63;
    const int wv   = tid >> 6;
    const float* bp = peaks + (size_t)blockIdx.x * NN * 3;
    float* bo = out + (size_t)blockIdx.x * NN * 3;
    volatile unsigned char* vst = state_;

    // ---- phase 0: zero counters + state ----
    {
        int t4 = tid << 2;
        *(uint4*)&cellidx[t4] = make_uint4(0,0,0,0);
        *(uint4*)&buckidx[t4] = make_uint4(0,0,0,0);
        *(unsigned*)&state_[t4] = 0u;
    }
    __syncthreads();                                           // B1

    // ---- phase 1: vectorized load (3x float4 = points 4t..4t+3) + count ----
    const float4* bp4 = (const float4*)bp;
    float4 f0 = bp4[tid*3+0], f1 = bp4[tid*3+1], f2 = bp4[tid*3+2];
    float xs[4] = {f0.x, f0.w, f1.z, f2.y};
    float ys[4] = {f0.y, f1.x, f1.w, f2.z};
    float cs[4] = {f0.z, f1.y, f2.x, f2.w};
    unsigned kb[4]; int cel[4], buck[4];
    #pragma unroll
    for (int k = 0; k < 4; ++k) {
        kb[k] = ~__float_as_uint(cs[k]);        // conf>=0 -> ascending kb == descending conf
        int cx = min((int)(xs[k] * 0.125f), 63);   // x*0.125 exact (pow2); trunc exact
        int cy = min((int)(ys[k] * 0.125f), 63);
        cel[k] = (cy << 6) | cx;
        atomicAdd(&cellidx[cel[k]], 1u);
        buck[k] = 4095 - min((int)__fmul_rn(cs[k], 4096.0f), 4095);  // monotone bucketing
        atomicAdd(&buckidx[buck[k]], 1u);
    }
    __syncthreads();                                           // B2

    // ---- phase 2: dual in-place exclusive scan ----
    {
        int t4 = tid << 2;
        unsigned a0=cellidx[t4], a1=cellidx[t4+1], a2=cellidx[t4+2], a3=cellidx[t4+3];
        unsigned b0=buckidx[t4], b1=buckidx[t4+1], b2=buckidx[t4+2], b3=buckidx[t4+3];
        unsigned sa = a0+a1+a2+a3, sb = b0+b1+b2+b3;
        unsigned ia = sa, ib = sb;
        for (int off = 1; off < 64; off <<= 1) {
            unsigned na = __shfl_up(ia, off);
            unsigned nb = __shfl_up(ib, off);
            if (lane >= off) { ia += na; ib += nb; }
        }
        if (lane == 63) { wavesumA[wv] = ia; wavesumB[wv] = ib; }
        __syncthreads();                                       // B3
        if (tid == 0) {
            unsigned acc = 0;
            for (int i = 0; i < 16; ++i) { unsigned t = wavesumA[i]; wavesumA[i] = acc; acc += t; }
            acc = 0;
            for (int i = 0; i < 16; ++i) { unsigned t = wavesumB[i]; wavesumB[i] = acc; acc += t; }
        }
        __syncthreads();                                       // B4
        unsigned baseA = wavesumA[wv] + (ia - sa);
        unsigned baseB = wavesumB[wv] + (ib - sb);
        cellidx[t4]=baseA; cellidx[t4+1]=baseA+a0; cellidx[t4+2]=baseA+a0+a1; cellidx[t4+3]=baseA+a0+a1+a2;
        buckidx[t4]=baseB; buckidx[t4+1]=baseB+b0; buckidx[t4+2]=baseB+b0+b1; buckidx[t4+3]=baseB+b0+b1+b2;
    }
    __syncthreads();                                           // B5

    // ---- phase 3: scatter from registers (cursors -> range ENDs) ----
    #pragma unroll
    for (int k = 0; k < 4; ++k) {
        int j = (tid << 2) | k;
        unsigned q = atomicAdd(&cellidx[cel[k]], 1u);
        cpk[q] = make_uint4(__float_as_uint(xs[k]), __float_as_uint(ys[k]), kb[k], (unsigned)j);
        unsigned q2 = atomicAdd(&buckidx[buck[k]], 1u);
        keybuf[q2] = ((unsigned long long)kb[k] << 32) | (unsigned)j;
    }
    __syncthreads();                                           // B6
    // ranges now: [c ? idx[c-1] : 0, idx[c])

    // full eval (exact greedy dataflow; optional neighbor-list build)
    auto evalFull = [&](float x, float y, unsigned kj, unsigned jj,
                        bool build, unsigned long long &nbr) -> int {
        int cx = min((int)(x * 0.125f), 63);
        int cy = min((int)(y * 0.125f), 63);
        float u = __fsub_rn(x, (float)(cx << 3));   // exact (Sterbenz)
        float v = __fsub_rn(y, (float)(cy << 3));
        int cx0 = (u < 4.0f) ? max(cx - 1, 0) : cx;
        int cy0 = (v < 4.0f) ? max(cy - 1, 0) : cy;
        int cx1 = min(cx0 + 1, 63), cy1 = min(cy0 + 1, 63);
        nbr = ~0ull;
        int nn_ = 0; bool ovf = false, anyundet = false;
        for (int cyy = cy0; cyy <= cy1; ++cyy) {
            for (int cxx = cx0; cxx <= cx1; ++cxx) {
                int c = (cyy << 6) | cxx;
                unsigned s = c ? cellidx[c-1] : 0;
                unsigned e = cellidx[c];
                for (unsigned q = s; q < e; ++q) {
                    uint4 pm = cpk[q];   // one ds_read_b128; adjacent lanes overlap -> broadcast
                    if (!(pm.z < kj || (pm.z == kj && pm.w < jj))) continue;   // earlier only
                    float dx  = __fsub_rn(__uint_as_float(pm.x), x);
                    float dyy = __fsub_rn(__uint_as_float(pm.y), y);
                    float d2  = __fadd_rn(__fmul_rn(dx, dx), __fmul_rn(dyy, dyy));
                    if (d2 < 16.0f) {
                        unsigned char st = vst[pm.w];
                        if (st == 1) return 2;          // KEPT is final -> safe
                        if (st == 0) {
                            anyundet = true;
                            if (build) {
                                if (nn_ < 4) {
                                    nbr &= ~(0xFFFFull << (nn_ * 16));
                                    nbr |= ((unsigned long long)pm.w) << (nn_ * 16);
                                    ++nn_;
                                } else ovf = true;
                            }
                        }
                    }
                }
            }
        }
        if (build && ovf) nbr = OVF_L;
        return anyundet ? 0 : 1;
    };

    // ---- phase 4a: rank my own points (replaces physical sort; O(1) indep reads) ----
    unsigned rnk[4];
    #pragma unroll
    for (int k = 0; k < 4; ++k) {
        int j = (tid << 2) | k;
        unsigned long long mykey = ((unsigned long long)kb[k] << 32) | (unsigned)j;
        unsigned s = buck[k] ? buckidx[buck[k]-1] : 0;
        unsigned e = buckidx[buck[k]];
        unsigned cnt = 0;
        for (unsigned q = s; q < e; ++q) cnt += (keybuf[q] < mykey) ? 1u : 0u;
        rnk[k] = s + cnt;
    }

    // ---- phase 4b: round-0 eval in CELL order, reg-resident state ----
    float ex[4], ey[4]; unsigned ekb[4], ej[4];
    unsigned long long list_[4]; int res[4];
    #pragma unroll
    for (int k = 0; k < 4; ++k) {
        int t = tid + (k << 10);
        uint4 pj = cpk[t];
        ex[k] = __uint_as_float(pj.x); ey[k] = __uint_as_float(pj.y);
        ekb[k] = pj.z; ej[k] = pj.w;
        res[k] = evalFull(ex[k], ey[k], ekb[k], ej[k], true, list_[k]);
        if (res[k]) state_[ej[k]] = (unsigned char)res[k];
    }
    __syncthreads();                                           // B7

    // ---- phase 5: list-driven rounds, 1 barrier each, regs only ----
    while (true) {
        int mine = 0;
        #pragma unroll
        for (int k = 0; k < 4; ++k) {
            if (res[k] == 0) {
                unsigned long long L = list_[k];
                int r;
                if (L != OVF_L) {
                    bool any1 = false, any0 = false;
                    #pragma unroll
                    for (int e = 0; e < 4; ++e) {
                        unsigned vv = (unsigned)((L >> (e * 16)) & 0xFFFFull);
                        if (vv < NN) {
                            unsigned char st = vst[vv];
                            any1 |= (st == 1);
                            any0 |= (st == 0);
                        }
                    }
                    r = any1 ? 2 : (any0 ? 0 : 1);
                } else {
                    unsigned long long d_;
                    r = evalFull(ex[k], ey[k], ekb[k], ej[k], false, d_);
                }
                if (r) { state_[ej[k]] = (unsigned char)r; res[k] = r; }
                else mine = 1;
            }
        }
        if (__syncthreads_count(mine) == 0) break;             // exit barrier = states final
    }

    // ---- phase 6: direct ranked output from registers (rank is a bijection) ----
    #pragma unroll
    for (int k = 0; k < 4; ++k) {
        int j = (tid << 2) | k;
        bool kp = (state_[j] == 1);
        unsigned r = rnk[k];
        bo[r*3+0] = kp ? xs[k] : 0.0f;
        bo[r*3+1] = kp ? ys[k] : 0.0f;
        bo[r*3+2] = kp ? cs[k] : 0.0f;
    }
}

extern "C" void kernel_launch(void* const* d_in, const int* in_sizes, int n_in,
                              void* d_out, int out_size, void* d_ws, size_t ws_size,
                              hipStream_t stream) {
    const float* peaks = (const float*)d_in[0];
    float* out = (float*)d_out;
    const int B = in_sizes[0] / (NN * 3);
    DistanceNMS_kernel<<<B, NT, 0, stream>>>(peaks, out);
}

// Round 8
// 46.056 us; speedup vs baseline: 1.4200x; 1.4200x over previous
//
#include <hip/hip_runtime.h>

#define NN 4096
#define NT 1024
#define OVF_L 0xFFFFFFFFFFFFFFFEull

__global__ __launch_bounds__(NT)
void DistanceNMS_kernel(const float* __restrict__ peaks, float* __restrict__ out)
{
    // ---- LDS (~132 KB) ----
    __shared__ unsigned long long cxy[NN];      // 32K cell-ordered {x_bits | y_bits<<32}
    __shared__ unsigned long long ckey[NN];     // 32K cell-ordered (kb<<32)|origidx
    __shared__ unsigned long long keybuf[NN];   // 32K bucket-grouped keys; after B7: lists[origidx]
    __shared__ unsigned cellidx[4096];          // 16K count -> excl start -> END
    __shared__ unsigned buckidx[4096];          // 16K count -> excl start -> END
    __shared__ unsigned char state_[NN];        //  4K by orig idx: 0=UNDET 1=KEPT 2=DEAD
    __shared__ unsigned wavesumA[16], wavesumB[16];

    const int tid  = threadIdx.x;
    const int lane = tid & 63;
    const int wv   = tid >> 6;
    const float* bp = peaks + (size_t)blockIdx.x * NN * 3;
    float* bo = out + (size_t)blockIdx.x * NN * 3;
    volatile unsigned char* vst = state_;
    unsigned long long* lists = keybuf;         // alias, valid after B7

    // ---- phase 0: zero counters + state ----
    {
        int t4 = tid << 2;
        *(uint4*)&cellidx[t4] = make_uint4(0,0,0,0);
        *(uint4*)&buckidx[t4] = make_uint4(0,0,0,0);
        *(unsigned*)&state_[t4] = 0u;
    }
    __syncthreads();                                           // B1

    // ---- phase 1: vectorized load (3x float4 = points 4t..4t+3) + count ----
    const float4* bp4 = (const float4*)bp;
    float4 f0 = bp4[tid*3+0], f1 = bp4[tid*3+1], f2 = bp4[tid*3+2];
    float xs[4] = {f0.x, f0.w, f1.z, f2.y};
    float ys[4] = {f0.y, f1.x, f1.w, f2.z};
    float cs[4] = {f0.z, f1.y, f2.x, f2.w};
    unsigned kb[4]; int cel[4], buck[4];
    #pragma unroll
    for (int k = 0; k < 4; ++k) {
        kb[k] = ~__float_as_uint(cs[k]);        // conf>=0 -> ascending kb == descending conf
        int cx = min((int)(xs[k] * 0.125f), 63);
        int cy = min((int)(ys[k] * 0.125f), 63);
        cel[k] = (cy << 6) | cx;
        atomicAdd(&cellidx[cel[k]], 1u);
        buck[k] = 4095 - min((int)__fmul_rn(cs[k], 4096.0f), 4095);  // monotone bucketing
        atomicAdd(&buckidx[buck[k]], 1u);
    }
    __syncthreads();                                           // B2

    // ---- phase 2: dual in-place exclusive scan ----
    {
        int t4 = tid << 2;
        unsigned a0=cellidx[t4], a1=cellidx[t4+1], a2=cellidx[t4+2], a3=cellidx[t4+3];
        unsigned b0=buckidx[t4], b1=buckidx[t4+1], b2=buckidx[t4+2], b3=buckidx[t4+3];
        unsigned sa = a0+a1+a2+a3, sb = b0+b1+b2+b3;
        unsigned ia = sa, ib = sb;
        for (int off = 1; off < 64; off <<= 1) {
            unsigned na = __shfl_up(ia, off);
            unsigned nb = __shfl_up(ib, off);
            if (lane >= off) { ia += na; ib += nb; }
        }
        if (lane == 63) { wavesumA[wv] = ia; wavesumB[wv] = ib; }
        __syncthreads();                                       // B3
        if (tid == 0) {
            unsigned acc = 0;
            for (int i = 0; i < 16; ++i) { unsigned t = wavesumA[i]; wavesumA[i] = acc; acc += t; }
            acc = 0;
            for (int i = 0; i < 16; ++i) { unsigned t = wavesumB[i]; wavesumB[i] = acc; acc += t; }
        }
        __syncthreads();                                       // B4
        unsigned baseA = wavesumA[wv] + (ia - sa);
        unsigned baseB = wavesumB[wv] + (ib - sb);
        cellidx[t4]=baseA; cellidx[t4+1]=baseA+a0; cellidx[t4+2]=baseA+a0+a1; cellidx[t4+3]=baseA+a0+a1+a2;
        buckidx[t4]=baseB; buckidx[t4+1]=baseB+b0; buckidx[t4+2]=baseB+b0+b1; buckidx[t4+3]=baseB+b0+b1+b2;
    }
    __syncthreads();                                           // B5

    // ---- phase 3: scatter from registers (cursors -> range ENDs) ----
    #pragma unroll
    for (int k = 0; k < 4; ++k) {
        int j = (tid << 2) | k;
        unsigned long long key = ((unsigned long long)kb[k] << 32) | (unsigned)j;
        unsigned q = atomicAdd(&cellidx[cel[k]], 1u);
        cxy[q]  = ((unsigned long long)__float_as_uint(ys[k]) << 32) | __float_as_uint(xs[k]);
        ckey[q] = key;
        unsigned q2 = atomicAdd(&buckidx[buck[k]], 1u);
        keybuf[q2] = key;
    }
    __syncthreads();                                           // B6
    // ranges now: [c ? idx[c-1] : 0, idx[c])

    // ---- phase 4a: rank my points (stable-sort permutation; O(1) indep reads) ----
    unsigned rnk[4];
    #pragma unroll
    for (int k = 0; k < 4; ++k) {
        int j = (tid << 2) | k;
        unsigned long long mykey = ((unsigned long long)kb[k] << 32) | (unsigned)j;
        unsigned s = buck[k] ? buckidx[buck[k]-1] : 0;
        unsigned e = buckidx[buck[k]];
        unsigned cnt = 0;
        for (unsigned q = s; q < e; ++q) cnt += (keybuf[q] < mykey) ? 1u : 0u;
        rnk[k] = s + cnt;
    }
    __syncthreads();                                           // B7: keybuf -> lists

    // ---- phase 4b: PURE-GEOMETRY neighbor-list build (cell-owner, no state reads) ----
    float ex[4], ey[4];
    unsigned long long ekey[4], myL[4];
    unsigned ej[4]; int res[4];
    #pragma unroll
    for (int k = 0; k < 4; ++k) {
        int t = tid + (k << 10);
        unsigned long long pxy = cxy[t];
        unsigned long long key = ckey[t];
        float x = __uint_as_float((unsigned)pxy);
        float y = __uint_as_float((unsigned)(pxy >> 32));
        ex[k] = x; ey[k] = y; ekey[k] = key; ej[k] = (unsigned)(key & 0xFFFFull);
        int cx = min((int)(x * 0.125f), 63);
        int cy = min((int)(y * 0.125f), 63);
        float u = __fsub_rn(x, (float)(cx << 3));   // exact (Sterbenz)
        float v = __fsub_rn(y, (float)(cy << 3));
        int cx0 = (u < 4.0f) ? max(cx - 1, 0) : cx;
        int cy0 = (v < 4.0f) ? max(cy - 1, 0) : cy;
        int cx1 = min(cx0 + 1, 63), cy1 = min(cy0 + 1, 63);
        unsigned long long L = ~0ull; int cnt = 0; bool ovf = false;
        for (int cyy = cy0; cyy <= cy1; ++cyy) {
            for (int cxx = cx0; cxx <= cx1; ++cxx) {
                int c = (cyy << 6) | cxx;
                unsigned s = c ? cellidx[c-1] : 0;
                unsigned e = cellidx[c];
                for (unsigned q = s; q < e; ++q) {
                    unsigned long long mxy = cxy[q];           // b64, pipelineable
                    float dx  = __fsub_rn(__uint_as_float((unsigned)mxy), x);
                    float dyy = __fsub_rn(__uint_as_float((unsigned)(mxy >> 32)), y);
                    float d2  = __fadd_rn(__fmul_rn(dx, dx), __fmul_rn(dyy, dyy));
                    if (d2 < 16.0f) {                          // ~20% taken
                        unsigned long long mk = ckey[q];
                        if (mk < key) {                        // earlier == smaller u64 key
                            if (cnt < 4) {
                                L &= ~(0xFFFFull << (cnt * 16));
                                L |= ((unsigned long long)(mk & 0xFFFFull)) << (cnt * 16);
                                ++cnt;
                            } else ovf = true;
                        }
                    }
                }
            }
        }
        if (ovf) L = OVF_L;
        myL[k] = L;
        lists[ej[k]] = L;
        res[k] = (!ovf && cnt == 0) ? 1 : 0;                   // no earlier nbr -> KEPT
        if (res[k]) state_[ej[k]] = 1;
    }
    __syncthreads();                                           // B8

    // ---- phase 5: 2-level lookahead rounds (exact monotone fixpoint) ----
    while (true) {
        int mine = 0;
        #pragma unroll
        for (int k = 0; k < 4; ++k) {
            if (res[k] == 0) {
                int r;
                unsigned long long L = myL[k];
                if (L != OVF_L) {
                    bool any1 = false, anyun = false;
                    #pragma unroll
                    for (int e2 = 0; e2 < 4; ++e2) {
                        unsigned vv = (unsigned)((L >> (e2 * 16)) & 0xFFFFull);
                        if (vv < NN) {
                            unsigned char st = vst[vv];
                            if (st == 1) any1 = true;
                            else if (st == 0) {
                                unsigned long long L2 = lists[vv];    // final post-B8
                                if (L2 == OVF_L) anyun = true;
                                else {
                                    bool a1 = false, a0 = false;
                                    #pragma unroll
                                    for (int e3 = 0; e3 < 4; ++e3) {
                                        unsigned ww = (unsigned)((L2 >> (e3 * 16)) & 0xFFFFull);
                                        if (ww < NN) {
                                            unsigned char s2 = vst[ww];
                                            a1 |= (s2 == 1); a0 |= (s2 == 0);
                                        }
                                    }
                                    if (a1) { /* m fresh-DEAD -> never kills me */ }
                                    else if (a0) anyun = true;
                                    else any1 = true;   // m fresh-KEPT -> I'm dead
                                }
                            }
                        }
                    }
                    r = any1 ? 2 : (anyun ? 0 : 1);
                } else {
                    // OVF (>4 earlier nbrs, rare): full re-eval via cells
                    float x = ex[k], y = ey[k];
                    unsigned long long key = ekey[k];
                    int cx = min((int)(x * 0.125f), 63), cy = min((int)(y * 0.125f), 63);
                    float u = __fsub_rn(x, (float)(cx << 3)), v = __fsub_rn(y, (float)(cy << 3));
                    int cx0 = (u < 4.0f) ? max(cx - 1, 0) : cx;
                    int cy0 = (v < 4.0f) ? max(cy - 1, 0) : cy;
                    int cx1 = min(cx0 + 1, 63), cy1 = min(cy0 + 1, 63);
                    bool anyun = false; r = 1;
                    for (int cyy = cy0; cyy <= cy1 && r != 2; ++cyy)
                    for (int cxx = cx0; cxx <= cx1 && r != 2; ++cxx) {
                        int c = (cyy << 6) | cxx;
                        unsigned s = c ? cellidx[c-1] : 0;
                        unsigned e = cellidx[c];
                        for (unsigned q = s; q < e; ++q) {
                            unsigned long long mxy = cxy[q];
                            float dx  = __fsub_rn(__uint_as_float((unsigned)mxy), x);
                            float dyy = __fsub_rn(__uint_as_float((unsigned)(mxy >> 32)), y);
                            float d2  = __fadd_rn(__fmul_rn(dx, dx), __fmul_rn(dyy, dyy));
                            if (d2 < 16.0f) {
                                unsigned long long mk = ckey[q];
                                if (mk < key) {
                                    unsigned char st = vst[(unsigned)(mk & 0xFFFFull)];
                                    if (st == 1) { r = 2; break; }
                                    if (st == 0) anyun = true;
                                }
                            }
                        }
                    }
                    if (r != 2) r = anyun ? 0 : 1;
                }
                if (r) { state_[ej[k]] = (unsigned char)r; res[k] = r; }
                else mine = 1;
            }
        }
        if (__syncthreads_count(mine) == 0) break;             // exit barrier: states final
    }

    // ---- phase 6: direct ranked output from registers (rank is a bijection) ----
    #pragma unroll
    for (int k = 0; k < 4; ++k) {
        int j = (tid << 2) | k;
        bool kp = (state_[j] == 1);
        unsigned r = rnk[k];
        bo[r*3+0] = kp ? xs[k] : 0.0f;
        bo[r*3+1] = kp ? ys[k] : 0.0f;
        bo[r*3+2] = kp ? cs[k] : 0.0f;
    }
}

extern "C" void kernel_launch(void* const* d_in, const int* in_sizes, int n_in,
                              void* d_out, int out_size, void* d_ws, size_t ws_size,
                              hipStream_t stream) {
    const float* peaks = (const float*)d_in[0];
    float* out = (float*)d_out;
    const int B = in_sizes[0] / (NN * 3);
    DistanceNMS_kernel<<<B, NT, 0, stream>>>(peaks, out);
}

// Round 9
// 40.959 us; speedup vs baseline: 1.5967x; 1.1244x over previous
//
#include <hip/hip_runtime.h>

#define NN 4096
#define NT 1024
#define OVF_L 0xFFFFFFFFFFFFFFFEull

__global__ __launch_bounds__(NT)
void DistanceNMS_kernel(const float* __restrict__ peaks, float* __restrict__ out)
{
    // ---- LDS (~132 KB) ----
    __shared__ unsigned long long big[2 * NN];  // 64K: cxy[0..4095] | ckey[4096..8191]; later: 48K output stage
    __shared__ unsigned long long keybuf[NN];   // 32K: bucket-grouped keys; after B7: lists[origidx]
    __shared__ unsigned cellidx[4096];          // 16K: count -> excl start -> END
    __shared__ unsigned buckidx[4096];          // 16K: count -> excl start -> END
    __shared__ unsigned char state_[NN];        //  4K: by orig idx: 0=UNDET 1=KEPT 2=DEAD
    __shared__ unsigned wavesumA[16], wavesumB[16];

    unsigned long long* cxy   = big;            // cell-ordered {x_bits | y_bits<<32}
    unsigned long long* ckey  = big + NN;       // cell-ordered (kb<<32)|origidx
    unsigned long long* lists = keybuf;         // valid after B7
    float* stage = (float*)big;                 // valid after fixpoint-exit barrier

    const int tid  = threadIdx.x;
    const int lane = tid & 63;
    const int wv   = tid >> 6;
    const float* bp = peaks + (size_t)blockIdx.x * NN * 3;
    float* bo = out + (size_t)blockIdx.x * NN * 3;
    volatile unsigned char* vst = state_;

    // ---- phase 0: zero counters + state ----
    {
        int t4 = tid << 2;
        *(uint4*)&cellidx[t4] = make_uint4(0,0,0,0);
        *(uint4*)&buckidx[t4] = make_uint4(0,0,0,0);
        *(unsigned*)&state_[t4] = 0u;
    }
    __syncthreads();                                           // B1

    // ---- phase 1: vectorized load (3x float4 = points 4t..4t+3) + count ----
    const float4* bp4 = (const float4*)bp;
    float4 f0 = bp4[tid*3+0], f1 = bp4[tid*3+1], f2 = bp4[tid*3+2];
    float xs[4] = {f0.x, f0.w, f1.z, f2.y};
    float ys[4] = {f0.y, f1.x, f1.w, f2.z};
    float cs[4] = {f0.z, f1.y, f2.x, f2.w};
    unsigned kb[4]; int cel[4], buck[4];
    #pragma unroll
    for (int k = 0; k < 4; ++k) {
        kb[k] = ~__float_as_uint(cs[k]);        // conf>=0 -> ascending kb == descending conf
        int cx = min((int)(xs[k] * 0.125f), 63);
        int cy = min((int)(ys[k] * 0.125f), 63);
        cel[k] = (cy << 6) | cx;
        atomicAdd(&cellidx[cel[k]], 1u);
        buck[k] = 4095 - min((int)__fmul_rn(cs[k], 4096.0f), 4095);  // monotone bucketing
        atomicAdd(&buckidx[buck[k]], 1u);
    }
    __syncthreads();                                           // B2

    // ---- phase 2: dual in-place exclusive scan (parallel wave-partial combine) ----
    {
        int t4 = tid << 2;
        unsigned a0=cellidx[t4], a1=cellidx[t4+1], a2=cellidx[t4+2], a3=cellidx[t4+3];
        unsigned b0=buckidx[t4], b1=buckidx[t4+1], b2=buckidx[t4+2], b3=buckidx[t4+3];
        unsigned sa = a0+a1+a2+a3, sb = b0+b1+b2+b3;
        unsigned ia = sa, ib = sb;
        for (int off = 1; off < 64; off <<= 1) {
            unsigned na = __shfl_up(ia, off);
            unsigned nb = __shfl_up(ib, off);
            if (lane >= off) { ia += na; ib += nb; }
        }
        if (lane == 63) { wavesumA[wv] = ia; wavesumB[wv] = ib; }
        __syncthreads();                                       // B3
        if (wv == 0) {                 // segmented 16-lane scan: lanes 0-15 = A, 16-31 = B
            unsigned val = (lane < 16) ? wavesumA[lane] : ((lane < 32) ? wavesumB[lane-16] : 0u);
            unsigned orig = val;
            for (int off = 1; off < 16; off <<= 1) {
                unsigned n = __shfl_up(val, off);
                if ((lane & 15) >= off) val += n;
            }
            val -= orig;               // exclusive
            if (lane < 16) wavesumA[lane] = val;
            else if (lane < 32) wavesumB[lane-16] = val;
        }
        __syncthreads();                                       // B4
        unsigned baseA = wavesumA[wv] + (ia - sa);
        unsigned baseB = wavesumB[wv] + (ib - sb);
        cellidx[t4]=baseA; cellidx[t4+1]=baseA+a0; cellidx[t4+2]=baseA+a0+a1; cellidx[t4+3]=baseA+a0+a1+a2;
        buckidx[t4]=baseB; buckidx[t4+1]=baseB+b0; buckidx[t4+2]=baseB+b0+b1; buckidx[t4+3]=baseB+b0+b1+b2;
    }
    __syncthreads();                                           // B5

    // ---- phase 3: scatter from registers (cursors -> range ENDs) ----
    #pragma unroll
    for (int k = 0; k < 4; ++k) {
        int j = (tid << 2) | k;
        unsigned long long key = ((unsigned long long)kb[k] << 32) | (unsigned)j;
        unsigned q = atomicAdd(&cellidx[cel[k]], 1u);
        cxy[q]  = ((unsigned long long)__float_as_uint(ys[k]) << 32) | __float_as_uint(xs[k]);
        ckey[q] = key;
        unsigned q2 = atomicAdd(&buckidx[buck[k]], 1u);
        keybuf[q2] = key;
    }
    __syncthreads();                                           // B6
    // ranges now: [c ? idx[c-1] : 0, idx[c])

    // ---- phase 4a: rank my points (stable-sort permutation; O(1) indep reads) ----
    unsigned rnk[4];
    #pragma unroll
    for (int k = 0; k < 4; ++k) {
        int j = (tid << 2) | k;
        unsigned long long mykey = ((unsigned long long)kb[k] << 32) | (unsigned)j;
        unsigned s = buck[k] ? buckidx[buck[k]-1] : 0;
        unsigned e = buckidx[buck[k]];
        unsigned cnt = 0;
        for (unsigned q = s; q < e; ++q) cnt += (keybuf[q] < mykey) ? 1u : 0u;
        rnk[k] = s + cnt;
    }
    __syncthreads();                                           // B7: keybuf -> lists

    // ---- phase 4b: PURE-GEOMETRY neighbor-list build (cell-owner, no state reads) ----
    float ex[4], ey[4];
    unsigned long long ekey[4], myL[4];
    unsigned ej[4]; int res[4];
    #pragma unroll
    for (int k = 0; k < 4; ++k) {
        int t = tid + (k << 10);
        unsigned long long pxy = cxy[t];
        unsigned long long key = ckey[t];
        float x = __uint_as_float((unsigned)pxy);
        float y = __uint_as_float((unsigned)(pxy >> 32));
        ex[k] = x; ey[k] = y; ekey[k] = key; ej[k] = (unsigned)(key & 0xFFFFull);
        int cx = min((int)(x * 0.125f), 63);
        int cy = min((int)(y * 0.125f), 63);
        float u = __fsub_rn(x, (float)(cx << 3));   // exact (Sterbenz)
        float v = __fsub_rn(y, (float)(cy << 3));
        int cx0 = (u < 4.0f) ? max(cx - 1, 0) : cx;
        int cy0 = (v < 4.0f) ? max(cy - 1, 0) : cy;
        int cx1 = min(cx0 + 1, 63), cy1 = min(cy0 + 1, 63);
        unsigned long long L = ~0ull; int cnt = 0; bool ovf = false;
        for (int cyy = cy0; cyy <= cy1; ++cyy) {
            for (int cxx = cx0; cxx <= cx1; ++cxx) {
                int c = (cyy << 6) | cxx;
                unsigned s = c ? cellidx[c-1] : 0;
                unsigned e = cellidx[c];
                for (unsigned q = s; q < e; ++q) {
                    unsigned long long mxy = cxy[q];           // b64, pipelineable
                    float dx  = __fsub_rn(__uint_as_float((unsigned)mxy), x);
                    float dyy = __fsub_rn(__uint_as_float((unsigned)(mxy >> 32)), y);
                    float d2  = __fadd_rn(__fmul_rn(dx, dx), __fmul_rn(dyy, dyy));
                    if (d2 < 16.0f) {                          // ~20% taken
                        unsigned long long mk = ckey[q];
                        if (mk < key) {                        // earlier == smaller u64 key
                            if (cnt < 4) {
                                L &= ~(0xFFFFull << (cnt * 16));
                                L |= ((unsigned long long)(mk & 0xFFFFull)) << (cnt * 16);
                                ++cnt;
                            } else ovf = true;
                        }
                    }
                }
            }
        }
        if (ovf) L = OVF_L;
        myL[k] = L;
        lists[ej[k]] = L;
        res[k] = (!ovf && cnt == 0) ? 1 : 0;                   // no earlier nbr -> KEPT
        if (res[k]) vst[ej[k]] = 1;
    }
    __syncthreads();                                           // B8: all lists published

    // ---- phase 5: BARRIER-FREE spin fixpoint with depth-2 lookahead ----
    // Spin iteration = <=4 volatile byte-reads (+ immutable list reads). Monotone
    // UNDET->{KEPT,DEAD}; LDS writes immediately visible; minimal undet point always
    // self-resolves -> termination. (r4's failed spin did full geometric re-evals.)
    while (res[0] == 0 || res[1] == 0 || res[2] == 0 || res[3] == 0) {
        #pragma unroll
        for (int k = 0; k < 4; ++k) {
            if (res[k] != 0) continue;
            int r;
            unsigned long long L = myL[k];
            if (L != OVF_L) {
                bool any1 = false, anyun = false;
                #pragma unroll
                for (int e2 = 0; e2 < 4; ++e2) {
                    unsigned vv = (unsigned)((L >> (e2 * 16)) & 0xFFFFull);
                    if (vv < NN) {
                        unsigned char st = vst[vv];
                        if (st == 1) any1 = true;
                        else if (st == 0) {
                            unsigned long long L2 = lists[vv];    // immutable post-B8
                            if (L2 == OVF_L) anyun = true;
                            else {
                                bool a1 = false, a0 = false;
                                #pragma unroll
                                for (int e3 = 0; e3 < 4; ++e3) {
                                    unsigned ww = (unsigned)((L2 >> (e3 * 16)) & 0xFFFFull);
                                    if (ww < NN) {
                                        unsigned char s2 = vst[ww];
                                        a1 |= (s2 == 1); a0 |= (s2 == 0);
                                    }
                                }
                                if (a1) { /* m fresh-DEAD -> never kills me */ }
                                else if (a0) anyun = true;
                                else any1 = true;   // m fresh-KEPT -> I'm dead
                            }
                        }
                    }
                }
                r = any1 ? 2 : (anyun ? 0 : 1);
            } else {
                // OVF (>4 earlier nbrs, rare): full re-eval via cells
                float x = ex[k], y = ey[k];
                unsigned long long key = ekey[k];
                int cx = min((int)(x * 0.125f), 63), cy = min((int)(y * 0.125f), 63);
                float u = __fsub_rn(x, (float)(cx << 3)), v = __fsub_rn(y, (float)(cy << 3));
                int cx0 = (u < 4.0f) ? max(cx - 1, 0) : cx;
                int cy0 = (v < 4.0f) ? max(cy - 1, 0) : cy;
                int cx1 = min(cx0 + 1, 63), cy1 = min(cy0 + 1, 63);
                bool anyun = false; r = 1;
                for (int cyy = cy0; cyy <= cy1 && r != 2; ++cyy)
                for (int cxx = cx0; cxx <= cx1 && r != 2; ++cxx) {
                    int c = (cyy << 6) | cxx;
                    unsigned s = c ? cellidx[c-1] : 0;
                    unsigned e = cellidx[c];
                    for (unsigned q = s; q < e; ++q) {
                        unsigned long long mxy = cxy[q];
                        float dx  = __fsub_rn(__uint_as_float((unsigned)mxy), x);
                        float dyy = __fsub_rn(__uint_as_float((unsigned)(mxy >> 32)), y);
                        float d2  = __fadd_rn(__fmul_rn(dx, dx), __fmul_rn(dyy, dyy));
                        if (d2 < 16.0f) {
                            unsigned long long mk = ckey[q];
                            if (mk < key) {
                                unsigned char st = vst[(unsigned)(mk & 0xFFFFull)];
                                if (st == 1) { r = 2; break; }
                                if (st == 0) anyun = true;
                            }
                        }
                    }
                }
                if (r != 2) r = anyun ? 0 : 1;
            }
            if (r) { vst[ej[k]] = (unsigned char)r; res[k] = r; }
        }
    }
    __syncthreads();                                           // B9: all states final; cxy/ckey dead

    // ---- phase 6: stage ranked output in LDS, then coalesced float4 writes ----
    #pragma unroll
    for (int k = 0; k < 4; ++k) {
        int j = (tid << 2) | k;
        bool kp = (state_[j] == 1);
        unsigned r = rnk[k];
        stage[r*3+0] = kp ? xs[k] : 0.0f;
        stage[r*3+1] = kp ? ys[k] : 0.0f;
        stage[r*3+2] = kp ? cs[k] : 0.0f;
    }
    __syncthreads();                                           // B10
    {
        const float4* st4 = (const float4*)stage;
        float4* bo4 = (float4*)bo;
        #pragma unroll
        for (int i = 0; i < 3; ++i)
            bo4[tid + (i << 10)] = st4[tid + (i << 10)];
    }
}

extern "C" void kernel_launch(void* const* d_in, const int* in_sizes, int n_in,
                              void* d_out, int out_size, void* d_ws, size_t ws_size,
                              hipStream_t stream) {
    const float* peaks = (const float*)d_in[0];
    float* out = (float*)d_out;
    const int B = in_sizes[0] / (NN * 3);
    DistanceNMS_kernel<<<B, NT, 0, stream>>>(peaks, out);
}

// Round 10
// 35.549 us; speedup vs baseline: 1.8397x; 1.1522x over previous
//
#include <hip/hip_runtime.h>

#define NN 4096
#define NT 1024
#define OVF_L 0xFFFFFFFFFFFFFFFEull

__global__ __launch_bounds__(NT)
void DistanceNMS_kernel(const float* __restrict__ peaks, float* __restrict__ out)
{
    // ---- LDS (~132 KB) ----
    __shared__ unsigned long long big[2 * NN];  // 64K: cxy | ckey; later: 48K output stage
    __shared__ unsigned long long keybuf[NN];   // 32K: bucket-grouped keys; after B7: lists[origidx]
    __shared__ unsigned cellidx[4096];          // 16K: count -> excl start -> END
    __shared__ unsigned buckidx[4096];          // 16K: count -> excl start -> END
    __shared__ unsigned char state_[NN];        //  4K: 0=UNDET 1=KEPT 2=DEAD (by orig idx)
    __shared__ unsigned wavesumA[16], wavesumB[16];

    unsigned long long* cxy   = big;            // cell-ordered {x_bits | y_bits<<32}
    unsigned long long* ckey  = big + NN;       // cell-ordered (kb<<32)|origidx
    unsigned long long* lists = keybuf;         // valid after B7 (immutable after B8)
    float* stage = (float*)big;                 // valid after B9

    const int tid  = threadIdx.x;
    const int lane = tid & 63;
    const int wv   = tid >> 6;
    const float* bp = peaks + (size_t)blockIdx.x * NN * 3;
    float* bo = out + (size_t)blockIdx.x * NN * 3;
    volatile unsigned char* vst = state_;

    // ---- issue global loads FIRST (latency hides under zeroing + B1) ----
    const float4* bp4 = (const float4*)bp;
    float4 f0 = bp4[tid*3+0], f1 = bp4[tid*3+1], f2 = bp4[tid*3+2];

    // ---- phase 0: zero counters + state ----
    {
        int t4 = tid << 2;
        *(uint4*)&cellidx[t4] = make_uint4(0,0,0,0);
        *(uint4*)&buckidx[t4] = make_uint4(0,0,0,0);
        *(unsigned*)&state_[t4] = 0u;
    }
    __syncthreads();                                           // B1

    // ---- phase 1: count (cells by position, buckets by conf) ----
    float xs[4] = {f0.x, f0.w, f1.z, f2.y};
    float ys[4] = {f0.y, f1.x, f1.w, f2.z};
    float cs[4] = {f0.z, f1.y, f2.x, f2.w};
    unsigned kb[4]; int cel[4], buck[4];
    #pragma unroll
    for (int k = 0; k < 4; ++k) {
        kb[k] = ~__float_as_uint(cs[k]);        // conf>=0 -> ascending kb == descending conf
        int cx = min((int)(xs[k] * 0.125f), 63);
        int cy = min((int)(ys[k] * 0.125f), 63);
        cel[k] = (cy << 6) | cx;
        atomicAdd(&cellidx[cel[k]], 1u);
        buck[k] = 4095 - min((int)__fmul_rn(cs[k], 4096.0f), 4095);  // monotone bucketing
        atomicAdd(&buckidx[buck[k]], 1u);
    }
    __syncthreads();                                           // B2

    // ---- phase 2: dual in-place exclusive scan ----
    {
        int t4 = tid << 2;
        unsigned a0=cellidx[t4], a1=cellidx[t4+1], a2=cellidx[t4+2], a3=cellidx[t4+3];
        unsigned b0=buckidx[t4], b1=buckidx[t4+1], b2=buckidx[t4+2], b3=buckidx[t4+3];
        unsigned sa = a0+a1+a2+a3, sb = b0+b1+b2+b3;
        unsigned ia = sa, ib = sb;
        for (int off = 1; off < 64; off <<= 1) {
            unsigned na = __shfl_up(ia, off);
            unsigned nb = __shfl_up(ib, off);
            if (lane >= off) { ia += na; ib += nb; }
        }
        if (lane == 63) { wavesumA[wv] = ia; wavesumB[wv] = ib; }
        __syncthreads();                                       // B3
        if (wv == 0) {                 // segmented 16-lane scan: lanes 0-15 = A, 16-31 = B
            unsigned val = (lane < 16) ? wavesumA[lane] : ((lane < 32) ? wavesumB[lane-16] : 0u);
            unsigned orig = val;
            for (int off = 1; off < 16; off <<= 1) {
                unsigned n = __shfl_up(val, off);
                if ((lane & 15) >= off) val += n;
            }
            val -= orig;               // exclusive
            if (lane < 16) wavesumA[lane] = val;
            else if (lane < 32) wavesumB[lane-16] = val;
        }
        __syncthreads();                                       // B4
        unsigned baseA = wavesumA[wv] + (ia - sa);
        unsigned baseB = wavesumB[wv] + (ib - sb);
        cellidx[t4]=baseA; cellidx[t4+1]=baseA+a0; cellidx[t4+2]=baseA+a0+a1; cellidx[t4+3]=baseA+a0+a1+a2;
        buckidx[t4]=baseB; buckidx[t4+1]=baseB+b0; buckidx[t4+2]=baseB+b0+b1; buckidx[t4+3]=baseB+b0+b1+b2;
    }
    __syncthreads();                                           // B5

    // ---- phase 3: scatter from registers (cursors -> range ENDs) ----
    #pragma unroll
    for (int k = 0; k < 4; ++k) {
        int j = (tid << 2) | k;
        unsigned long long key = ((unsigned long long)kb[k] << 32) | (unsigned)j;
        unsigned q = atomicAdd(&cellidx[cel[k]], 1u);
        cxy[q]  = ((unsigned long long)__float_as_uint(ys[k]) << 32) | __float_as_uint(xs[k]);
        ckey[q] = key;
        unsigned q2 = atomicAdd(&buckidx[buck[k]], 1u);
        keybuf[q2] = key;
    }
    __syncthreads();                                           // B6
    // ranges now: [c ? idx[c-1] : 0, idx[c])

    // ---- phase 4a: rank my points (stable-sort permutation; O(1) indep reads) ----
    unsigned rnk[4];
    #pragma unroll
    for (int k = 0; k < 4; ++k) {
        int j = (tid << 2) | k;
        unsigned long long mykey = ((unsigned long long)kb[k] << 32) | (unsigned)j;
        unsigned s = buck[k] ? buckidx[buck[k]-1] : 0;
        unsigned e = buckidx[buck[k]];
        unsigned cnt = 0;
        for (unsigned q = s; q < e; ++q) cnt += (keybuf[q] < mykey) ? 1u : 0u;
        rnk[k] = s + cnt;
    }
    __syncthreads();                                           // B7: keybuf -> lists

    // ---- phase 4b: PURE-GEOMETRY neighbor-list build (row-merged ranges) ----
    float ex[4], ey[4];
    unsigned long long ekey[4], myL[4];
    unsigned ej[4]; int res[4];
    #pragma unroll
    for (int k = 0; k < 4; ++k) {
        int t = tid + (k << 10);
        unsigned long long pxy = cxy[t];
        unsigned long long key = ckey[t];
        float x = __uint_as_float((unsigned)pxy);
        float y = __uint_as_float((unsigned)(pxy >> 32));
        ex[k] = x; ey[k] = y; ekey[k] = key; ej[k] = (unsigned)(key & 0xFFFFull);
        int cx = min((int)(x * 0.125f), 63);
        int cy = min((int)(y * 0.125f), 63);
        float u = __fsub_rn(x, (float)(cx << 3));   // exact (Sterbenz)
        float v = __fsub_rn(y, (float)(cy << 3));
        int cx0 = (u < 4.0f) ? max(cx - 1, 0) : cx;
        int cy0 = (v < 4.0f) ? max(cy - 1, 0) : cy;
        int cx1 = min(cx0 + 1, 63), cy1 = min(cy0 + 1, 63);
        unsigned long long L = ~0ull; int cnt = 0; bool ovf = false;
        for (int cyy = cy0; cyy <= cy1; ++cyy) {
            int c0 = (cyy << 6) | cx0;                  // cells in a row are contiguous
            unsigned s = c0 ? cellidx[c0-1] : 0;
            unsigned e = cellidx[(cyy << 6) | cx1];
            for (unsigned q = s; q < e; ++q) {
                unsigned long long mxy = cxy[q];        // b64, pipelineable
                float dx  = __fsub_rn(__uint_as_float((unsigned)mxy), x);
                float dyy = __fsub_rn(__uint_as_float((unsigned)(mxy >> 32)), y);
                float d2  = __fadd_rn(__fmul_rn(dx, dx), __fmul_rn(dyy, dyy));
                if (d2 < 16.0f) {                       // ~20% taken
                    unsigned long long mk = ckey[q];
                    if (mk < key) {                     // earlier == smaller u64 key
                        if (cnt < 4) {
                            L &= ~(0xFFFFull << (cnt * 16));
                            L |= ((unsigned long long)(mk & 0xFFFFull)) << (cnt * 16);
                            ++cnt;
                        } else ovf = true;
                    }
                }
            }
        }
        if (ovf) L = OVF_L;
        myL[k] = L;
        lists[ej[k]] = L;
        res[k] = (!ovf && cnt == 0) ? 1 : 0;            // no earlier nbr -> KEPT
        if (res[k]) vst[ej[k]] = 1;
    }
    __syncthreads();                                           // B8: lists published (immutable)

    // ---- phase 5: barrier-free spin fixpoint, depth-2 lookahead + entry PRUNING ----
    // Register copy myL[k] is pruned (0xFFFF) as neighbors become finally-DEAD
    // (directly or via lookahead) -> probe width shrinks monotonically. LDS lists[]
    // keeps the original build-time value for lookahead readers. Monotone states,
    // minimal undet always self-resolves -> termination.
    while (res[0] == 0 || res[1] == 0 || res[2] == 0 || res[3] == 0) {
        #pragma unroll
        for (int k = 0; k < 4; ++k) {
            if (res[k] != 0) continue;
            int r;
            unsigned long long L = myL[k];
            if (L != OVF_L) {
                bool dead = false, anyun = false;
                #pragma unroll
                for (int e2 = 0; e2 < 4; ++e2) {
                    unsigned vv = (unsigned)((L >> (e2 * 16)) & 0xFFFFull);
                    if (vv < NN) {
                        unsigned char st = vst[vv];
                        if (st == 1) dead = true;
                        else if (st == 2) L |= (0xFFFFull << (e2 * 16));   // prune
                        else {
                            unsigned long long L2 = lists[vv];    // immutable post-B8
                            if (L2 == OVF_L) anyun = true;
                            else {
                                bool a1 = false, a0 = false;
                                #pragma unroll
                                for (int e3 = 0; e3 < 4; ++e3) {
                                    unsigned ww = (unsigned)((L2 >> (e3 * 16)) & 0xFFFFull);
                                    if (ww < NN) {
                                        unsigned char s2 = vst[ww];
                                        a1 |= (s2 == 1); a0 |= (s2 == 0);
                                    }
                                }
                                if (a1) L |= (0xFFFFull << (e2 * 16));     // vv final-dead -> prune
                                else if (a0) anyun = true;
                                else dead = true;                          // vv final-kept -> I'm dead
                            }
                        }
                    }
                }
                myL[k] = L;
                r = dead ? 2 : (anyun ? 0 : 1);         // all pruned -> KEPT
            } else {
                // OVF (>4 earlier nbrs, rare): full re-eval via cells (row-merged)
                float x = ex[k], y = ey[k];
                unsigned long long key = ekey[k];
                int cx = min((int)(x * 0.125f), 63), cy = min((int)(y * 0.125f), 63);
                float u = __fsub_rn(x, (float)(cx << 3)), v = __fsub_rn(y, (float)(cy << 3));
                int cx0 = (u < 4.0f) ? max(cx - 1, 0) : cx;
                int cy0 = (v < 4.0f) ? max(cy - 1, 0) : cy;
                int cx1 = min(cx0 + 1, 63), cy1 = min(cy0 + 1, 63);
                bool anyun = false; r = 1;
                for (int cyy = cy0; cyy <= cy1 && r != 2; ++cyy) {
                    int c0 = (cyy << 6) | cx0;
                    unsigned s = c0 ? cellidx[c0-1] : 0;
                    unsigned e = cellidx[(cyy << 6) | cx1];
                    for (unsigned q = s; q < e; ++q) {
                        unsigned long long mxy = cxy[q];
                        float dx  = __fsub_rn(__uint_as_float((unsigned)mxy), x);
                        float dyy = __fsub_rn(__uint_as_float((unsigned)(mxy >> 32)), y);
                        float d2  = __fadd_rn(__fmul_rn(dx, dx), __fmul_rn(dyy, dyy));
                        if (d2 < 16.0f) {
                            unsigned long long mk = ckey[q];
                            if (mk < key) {
                                unsigned char st = vst[(unsigned)(mk & 0xFFFFull)];
                                if (st == 1) { r = 2; break; }
                                if (st == 0) anyun = true;
                            }
                        }
                    }
                }
                if (r != 2) r = anyun ? 0 : 1;
            }
            if (r) { vst[ej[k]] = (unsigned char)r; res[k] = r; }
        }
    }
    __syncthreads();                                           // B9: states final; cxy/ckey dead

    // ---- phase 6: stage ranked output in LDS, then coalesced float4 writes ----
    #pragma unroll
    for (int k = 0; k < 4; ++k) {
        int j = (tid << 2) | k;
        bool kp = (state_[j] == 1);
        unsigned r = rnk[k];
        stage[r*3+0] = kp ? xs[k] : 0.0f;
        stage[r*3+1] = kp ? ys[k] : 0.0f;
        stage[r*3+2] = kp ? cs[k] : 0.0f;
    }
    __syncthreads();                                           // B10
    {
        const float4* st4 = (const float4*)stage;
        float4* bo4 = (float4*)bo;
        #pragma unroll
        for (int i = 0; i < 3; ++i)
            bo4[tid + (i << 10)] = st4[tid + (i << 10)];
    }
}

extern "C" void kernel_launch(void* const* d_in, const int* in_sizes, int n_in,
                              void* d_out, int out_size, void* d_ws, size_t ws_size,
                              hipStream_t stream) {
    const float* peaks = (const float*)d_in[0];
    float* out = (float*)d_out;
    const int B = in_sizes[0] / (NN * 3);
    DistanceNMS_kernel<<<B, NT, 0, stream>>>(peaks, out);
}

// Round 11
// 35.337 us; speedup vs baseline: 1.8507x; 1.0060x over previous
//
#include <hip/hip_runtime.h>

#define NN 4096
#define NT 1024
#define OVF_L  0xFFFFFFFFFFFFFFFEull
#define OVF_32 0xFFFFFFFEu

__global__ __launch_bounds__(NT)
void DistanceNMS_kernel(const float* __restrict__ peaks, float* __restrict__ out)
{
    // ---- LDS (~148 KB) ----
    __shared__ unsigned long long big[2 * NN];  // 64K: cxy | ckey; later: 48K output stage
    __shared__ unsigned long long keybuf[NN];   // 32K: bucket-grouped keys (stays live)
    __shared__ unsigned cellidx[4096];          // 16K: count -> excl start -> END
    __shared__ unsigned buckidx[4096];          // 16K: count -> excl start -> END
    __shared__ unsigned lists32[NN];            // 16K: 2x u16 earlier-nbrs (or OVF_32), by orig idx
    __shared__ unsigned char state_[NN];        //  4K: 0=UNDET 1=KEPT 2=DEAD (by orig idx)
    __shared__ unsigned wavesumA[16], wavesumB[16];

    unsigned long long* cxy  = big;             // cell-ordered {x_bits | y_bits<<32}
    unsigned long long* ckey = big + NN;        // cell-ordered (kb<<32)|origidx
    float* stage = (float*)big;                 // valid after spin-exit barrier

    const int tid  = threadIdx.x;
    const int lane = tid & 63;
    const int wv   = tid >> 6;
    const float* bp = peaks + (size_t)blockIdx.x * NN * 3;
    float* bo = out + (size_t)blockIdx.x * NN * 3;
    volatile unsigned char* vst = state_;

    // ---- issue global loads FIRST (latency hides under zeroing + B1) ----
    const float4* bp4 = (const float4*)bp;
    float4 f0 = bp4[tid*3+0], f1 = bp4[tid*3+1], f2 = bp4[tid*3+2];

    // ---- phase 0: zero counters + state ----
    {
        int t4 = tid << 2;
        *(uint4*)&cellidx[t4] = make_uint4(0,0,0,0);
        *(uint4*)&buckidx[t4] = make_uint4(0,0,0,0);
        *(unsigned*)&state_[t4] = 0u;
    }
    __syncthreads();                                           // B1

    // ---- phase 1: count (cells by position, buckets by conf) ----
    float xs[4] = {f0.x, f0.w, f1.z, f2.y};
    float ys[4] = {f0.y, f1.x, f1.w, f2.z};
    float cs[4] = {f0.z, f1.y, f2.x, f2.w};
    unsigned kb[4]; int cel[4], buck[4];
    #pragma unroll
    for (int k = 0; k < 4; ++k) {
        kb[k] = ~__float_as_uint(cs[k]);        // conf>=0 -> ascending kb == descending conf
        int cx = min((int)(xs[k] * 0.125f), 63);
        int cy = min((int)(ys[k] * 0.125f), 63);
        cel[k] = (cy << 6) | cx;
        atomicAdd(&cellidx[cel[k]], 1u);
        buck[k] = 4095 - min((int)__fmul_rn(cs[k], 4096.0f), 4095);  // monotone bucketing
        atomicAdd(&buckidx[buck[k]], 1u);
    }
    __syncthreads();                                           // B2

    // ---- phase 2: dual in-place exclusive scan ----
    {
        int t4 = tid << 2;
        unsigned a0=cellidx[t4], a1=cellidx[t4+1], a2=cellidx[t4+2], a3=cellidx[t4+3];
        unsigned b0=buckidx[t4], b1=buckidx[t4+1], b2=buckidx[t4+2], b3=buckidx[t4+3];
        unsigned sa = a0+a1+a2+a3, sb = b0+b1+b2+b3;
        unsigned ia = sa, ib = sb;
        for (int off = 1; off < 64; off <<= 1) {
            unsigned na = __shfl_up(ia, off);
            unsigned nb = __shfl_up(ib, off);
            if (lane >= off) { ia += na; ib += nb; }
        }
        if (lane == 63) { wavesumA[wv] = ia; wavesumB[wv] = ib; }
        __syncthreads();                                       // B3
        if (wv == 0) {                 // segmented 16-lane scan: lanes 0-15 = A, 16-31 = B
            unsigned val = (lane < 16) ? wavesumA[lane] : ((lane < 32) ? wavesumB[lane-16] : 0u);
            unsigned orig = val;
            for (int off = 1; off < 16; off <<= 1) {
                unsigned n = __shfl_up(val, off);
                if ((lane & 15) >= off) val += n;
            }
            val -= orig;               // exclusive
            if (lane < 16) wavesumA[lane] = val;
            else if (lane < 32) wavesumB[lane-16] = val;
        }
        __syncthreads();                                       // B4
        unsigned baseA = wavesumA[wv] + (ia - sa);
        unsigned baseB = wavesumB[wv] + (ib - sb);
        cellidx[t4]=baseA; cellidx[t4+1]=baseA+a0; cellidx[t4+2]=baseA+a0+a1; cellidx[t4+3]=baseA+a0+a1+a2;
        buckidx[t4]=baseB; buckidx[t4+1]=baseB+b0; buckidx[t4+2]=baseB+b0+b1; buckidx[t4+3]=baseB+b0+b1+b2;
    }
    __syncthreads();                                           // B5

    // ---- phase 3: scatter from registers (cursors -> range ENDs) ----
    #pragma unroll
    for (int k = 0; k < 4; ++k) {
        int j = (tid << 2) | k;
        unsigned long long key = ((unsigned long long)kb[k] << 32) | (unsigned)j;
        unsigned q = atomicAdd(&cellidx[cel[k]], 1u);
        cxy[q]  = ((unsigned long long)__float_as_uint(ys[k]) << 32) | __float_as_uint(xs[k]);
        ckey[q] = key;
        unsigned q2 = atomicAdd(&buckidx[buck[k]], 1u);
        keybuf[q2] = key;
    }
    __syncthreads();                                           // B6
    // ranges now: [c ? idx[c-1] : 0, idx[c])

    // ---- phase 4 (MERGED): rank + pure-geometry neighbor-list build, one interval ----
    // rank: independent bucket reads; build: dependent candidate chains -> ILP overlap.
    unsigned rnk[4];
    #pragma unroll
    for (int k = 0; k < 4; ++k) {
        int j = (tid << 2) | k;
        unsigned long long mykey = ((unsigned long long)kb[k] << 32) | (unsigned)j;
        unsigned s = buck[k] ? buckidx[buck[k]-1] : 0;
        unsigned e = buckidx[buck[k]];
        unsigned cnt = 0;
        for (unsigned q = s; q < e; ++q) cnt += (keybuf[q] < mykey) ? 1u : 0u;
        rnk[k] = s + cnt;
    }

    float ex[4], ey[4];
    unsigned long long ekey[4], myL[4];
    unsigned ej[4]; int res[4];
    #pragma unroll
    for (int k = 0; k < 4; ++k) {
        int t = tid + (k << 10);
        unsigned long long pxy = cxy[t];
        unsigned long long key = ckey[t];
        float x = __uint_as_float((unsigned)pxy);
        float y = __uint_as_float((unsigned)(pxy >> 32));
        ex[k] = x; ey[k] = y; ekey[k] = key; ej[k] = (unsigned)(key & 0xFFFFull);
        int cx = min((int)(x * 0.125f), 63);
        int cy = min((int)(y * 0.125f), 63);
        float u = __fsub_rn(x, (float)(cx << 3));   // exact (Sterbenz)
        float v = __fsub_rn(y, (float)(cy << 3));
        int cx0 = (u < 4.0f) ? max(cx - 1, 0) : cx;
        int cy0 = (v < 4.0f) ? max(cy - 1, 0) : cy;
        int cx1 = min(cx0 + 1, 63), cy1 = min(cy0 + 1, 63);
        unsigned long long L = ~0ull;
        unsigned w32 = 0xFFFFFFFFu;
        int cnt = 0; bool ovf = false;
        for (int cyy = cy0; cyy <= cy1; ++cyy) {
            int c0 = (cyy << 6) | cx0;                  // cells in a row are contiguous
            unsigned s = c0 ? cellidx[c0-1] : 0;
            unsigned e = cellidx[(cyy << 6) | cx1];
            for (unsigned q = s; q < e; ++q) {
                unsigned long long mxy = cxy[q];        // b64, pipelineable
                float dx  = __fsub_rn(__uint_as_float((unsigned)mxy), x);
                float dyy = __fsub_rn(__uint_as_float((unsigned)(mxy >> 32)), y);
                float d2  = __fadd_rn(__fmul_rn(dx, dx), __fmul_rn(dyy, dyy));
                if (d2 < 16.0f) {                       // ~20% taken
                    unsigned long long mk = ckey[q];
                    if (mk < key) {                     // earlier == smaller u64 key
                        unsigned mi = (unsigned)(mk & 0xFFFFull);
                        if (cnt < 4) {
                            L &= ~(0xFFFFull << (cnt * 16));
                            L |= ((unsigned long long)mi) << (cnt * 16);
                            if (cnt < 2) {
                                w32 &= ~(0xFFFFu << (cnt * 16));
                                w32 |= mi << (cnt * 16);
                            }
                            ++cnt;
                        } else ovf = true;
                    }
                }
            }
        }
        if (ovf) L = OVF_L;
        if (cnt > 2) w32 = OVF_32;                      // LDS list capped at 2 entries
        myL[k] = L;
        lists32[ej[k]] = w32;
        res[k] = (!ovf && cnt == 0) ? 1 : 0;            // no earlier nbr -> KEPT
        if (res[k]) vst[ej[k]] = 1;
    }
    __syncthreads();                                           // B7: lists published (immutable)

    // ---- phase 5: barrier-free spin fixpoint, depth-2 lookahead + entry PRUNING ----
    // Register myL[k] pruned (0xFFFF) as neighbors become finally-DEAD (directly or
    // via lookahead). LDS lists32[] is immutable build-time geometry. Monotone states,
    // minimal undet always self-resolves -> termination.
    while (res[0] == 0 || res[1] == 0 || res[2] == 0 || res[3] == 0) {
        #pragma unroll
        for (int k = 0; k < 4; ++k) {
            if (res[k] != 0) continue;
            int r;
            unsigned long long L = myL[k];
            if (L != OVF_L) {
                bool dead = false, anyun = false;
                #pragma unroll
                for (int e2 = 0; e2 < 4; ++e2) {
                    unsigned vv = (unsigned)((L >> (e2 * 16)) & 0xFFFFull);
                    if (vv < NN) {
                        unsigned char st = vst[vv];
                        if (st == 1) dead = true;
                        else if (st == 2) L |= (0xFFFFull << (e2 * 16));   // prune
                        else {
                            unsigned w2 = lists32[vv];            // immutable post-B7
                            if (w2 == OVF_32) anyun = true;
                            else {
                                bool a1 = false, a0 = false;
                                #pragma unroll
                                for (int e3 = 0; e3 < 2; ++e3) {
                                    unsigned ww = (w2 >> (e3 * 16)) & 0xFFFFu;
                                    if (ww < NN) {
                                        unsigned char s2 = vst[ww];
                                        a1 |= (s2 == 1); a0 |= (s2 == 0);
                                    }
                                }
                                if (a1) L |= (0xFFFFull << (e2 * 16));     // vv final-dead -> prune
                                else if (a0) anyun = true;
                                else dead = true;                          // vv final-kept -> I'm dead
                            }
                        }
                    }
                }
                myL[k] = L;
                r = dead ? 2 : (anyun ? 0 : 1);         // all pruned -> KEPT
            } else {
                // OVF (>4 earlier nbrs, rare): full re-eval via cells (row-merged)
                float x = ex[k], y = ey[k];
                unsigned long long key = ekey[k];
                int cx = min((int)(x * 0.125f), 63), cy = min((int)(y * 0.125f), 63);
                float u = __fsub_rn(x, (float)(cx << 3)), v = __fsub_rn(y, (float)(cy << 3));
                int cx0 = (u < 4.0f) ? max(cx - 1, 0) : cx;
                int cy0 = (v < 4.0f) ? max(cy - 1, 0) : cy;
                int cx1 = min(cx0 + 1, 63), cy1 = min(cy0 + 1, 63);
                bool anyun = false; r = 1;
                for (int cyy = cy0; cyy <= cy1 && r != 2; ++cyy) {
                    int c0 = (cyy << 6) | cx0;
                    unsigned s = c0 ? cellidx[c0-1] : 0;
                    unsigned e = cellidx[(cyy << 6) | cx1];
                    for (unsigned q = s; q < e; ++q) {
                        unsigned long long mxy = cxy[q];
                        float dx  = __fsub_rn(__uint_as_float((unsigned)mxy), x);
                        float dyy = __fsub_rn(__uint_as_float((unsigned)(mxy >> 32)), y);
                        float d2  = __fadd_rn(__fmul_rn(dx, dx), __fmul_rn(dyy, dyy));
                        if (d2 < 16.0f) {
                            unsigned long long mk = ckey[q];
                            if (mk < key) {
                                unsigned char st = vst[(unsigned)(mk & 0xFFFFull)];
                                if (st == 1) { r = 2; break; }
                                if (st == 0) anyun = true;
                            }
                        }
                    }
                }
                if (r != 2) r = anyun ? 0 : 1;
            }
            if (r) { vst[ej[k]] = (unsigned char)r; res[k] = r; }
        }
    }
    __syncthreads();                                           // B8: states final; cxy/ckey dead

    // ---- phase 6: stage ranked output in LDS, then coalesced float4 writes ----
    #pragma unroll
    for (int k = 0; k < 4; ++k) {
        int j = (tid << 2) | k;
        bool kp = (state_[j] == 1);
        unsigned r = rnk[k];
        stage[r*3+0] = kp ? xs[k] : 0.0f;
        stage[r*3+1] = kp ? ys[k] : 0.0f;
        stage[r*3+2] = kp ? cs[k] : 0.0f;
    }
    __syncthreads();                                           // B9
    {
        const float4* st4 = (const float4*)stage;
        float4* bo4 = (float4*)bo;
        #pragma unroll
        for (int i = 0; i < 3; ++i)
            bo4[tid + (i << 10)] = st4[tid + (i << 10)];
    }
}

extern "C" void kernel_launch(void* const* d_in, const int* in_sizes, int n_in,
                              void* d_out, int out_size, void* d_ws, size_t ws_size,
                              hipStream_t stream) {
    const float* peaks = (const float*)d_in[0];
    float* out = (float*)d_out;
    const int B = in_sizes[0] / (NN * 3);
    DistanceNMS_kernel<<<B, NT, 0, stream>>>(peaks, out);
}